// Round 6
// baseline (68.208 us; speedup 1.0000x reference)
//
#include <hip/hip_runtime.h>

// GenODE: z'(t) = tanh(z W1 + b1) W2 + b2, z_i(t_i) from z_i(0)=z_end[i],
// t_i = i/(N-1). SINGLE MIDPOINT (RK2) step with h = t_i:
//   k1 = f(z0); zmid = z0 + (h/2) k1; k2 = f(zmid); z1 = z0 + h k2.
// Validated R5: absmax sits at the bf16 compare floor (0.0078125 bit-exact).
//
// R5 decomposition: kernel ~19.4 us = ~4.6 us stages + ~15 us per-block
// setup (every block loads full W1+W2 = 128 KB; 512 blocks = 64 MB L2).
// R6 experiment: E=8 elems/block, 256 blocks, 1 block/CU -> halves weight
// traffic and per-CU setup instances. Per-element arithmetic is bit-identical
// to R5 (same sum order), so absmax must stay exactly 0.0078125.
//
// Per f-eval: phase1 thread j computes hidden j for E elems (z read as
// wave-broadcast ds_read_b128, ~free); phase2 thread (d=t&31, chunk=t>>5)
// contracts its 32-hidden chunk (W2 slice in regs), shfl_down(32) folds
// chunk pairs, per-wave partials via LDS; phase3 threads 0..E*D-1 hold RK2
// state in registers. 3 barriers per f-eval.

constexpr int D = 32;
constexpr int H = 512;
constexpr int E = 8;

__device__ __forceinline__ float fast_tanh(float x) {
    // tanh(x) = 1 - 2/(exp(2x)+1); overflow -> inf -> rcp -> 0 -> +1 (correct)
    float e = __expf(2.0f * x);
    float r = __builtin_amdgcn_rcpf(e + 1.0f);
    return 1.0f - 2.0f * r;
}

__global__ __launch_bounds__(512, 2) void ode_kernel(
    const float* __restrict__ z_end, const float* __restrict__ W1,
    const float* __restrict__ b1, const float* __restrict__ W2,
    const float* __restrict__ b2, float* __restrict__ out, int n)
{
    __shared__ __align__(16) float zin_s[E][D];     // stage input z (1 KB)
    __shared__ __align__(16) float h_s[E][H];       // hidden activations (16 KB)
    __shared__ __align__(16) float ws[E][8][D];     // per-wave partials (8 KB)

    const int t  = (int)threadIdx.x;
    const int c_ = t >> 5;      // hidden chunk, 16 chunks of 32
    const int wv = t >> 6;      // wave id (8 waves)
    const int ln = t & 63;      // lane id

    const int base = (int)blockIdx.x * E;

    // Register-resident weights.
    float w1c[D];
#pragma unroll
    for (int d = 0; d < D; ++d) w1c[d] = W1[d * H + t];       // coalesced over t
    const float b1j = b1[t];
    float w2t[D];
#pragma unroll
    for (int k = 0; k < D; ++k) w2t[k] = W2[(c_ * 32 + k) * D + (t & 31)];

    // Phase-3 per-thread ODE state (threads 0..E*D-1: e3 = t>>5, d3 = t&31).
    float zc = 0.0f, b2d = 0.0f, he = 0.0f;
    if (t < E * D) {
        const int e3 = t >> 5, d3 = t & 31;
        zc  = z_end[(base + e3) * D + d3];
        b2d = b2[d3];
        he  = (float)(base + e3) / (float)(n - 1);   // h = t_i (single step)
        zin_s[e3][d3] = zc;
    }
    __syncthreads();

#pragma unroll
    for (int stage = 0; stage < 2; ++stage) {
        // ---- phase1: hidden_j = tanh(zin . W1col_j + b1_j), all E elems ----
        float a[E];
#pragma unroll
        for (int e = 0; e < E; ++e) {
            const float4* z4 = (const float4*)zin_s[e];   // broadcast b128 reads
            float acc = b1j;
#pragma unroll
            for (int q = 0; q < 8; ++q) {
                float4 zv = z4[q];
                acc = fmaf(zv.x, w1c[4 * q + 0], acc);
                acc = fmaf(zv.y, w1c[4 * q + 1], acc);
                acc = fmaf(zv.z, w1c[4 * q + 2], acc);
                acc = fmaf(zv.w, w1c[4 * q + 3], acc);
            }
            a[e] = acc;
        }
#pragma unroll
        for (int e = 0; e < E; ++e) h_s[e][t] = fast_tanh(a[e]);
        __syncthreads();

        // ---- phase2: chunk-partial of k_d = sum_j h_j W2[j][d] ----
        float p[E];
#pragma unroll
        for (int e = 0; e < E; ++e) {
            const float4* h4 = (const float4*)&h_s[e][c_ * 32];
            float acc = 0.0f;
#pragma unroll
            for (int q = 0; q < 8; ++q) {
                float4 hv = h4[q];
                acc = fmaf(hv.x, w2t[4 * q + 0], acc);
                acc = fmaf(hv.y, w2t[4 * q + 1], acc);
                acc = fmaf(hv.z, w2t[4 * q + 2], acc);
                acc = fmaf(hv.w, w2t[4 * q + 3], acc);
            }
            p[e] = acc;
        }
#pragma unroll
        for (int e = 0; e < E; ++e) p[e] += __shfl_down(p[e], 32);
        if (ln < 32) {
#pragma unroll
            for (int e = 0; e < E; ++e) ws[e][wv][ln] = p[e];
        }
        __syncthreads();

        // ---- phase3: finish k_d, RK2 stage update (threads 0..E*D-1) ----
        if (t < E * D) {
            const int e3 = t >> 5, d3 = t & 31;
            float kd = b2d;
#pragma unroll
            for (int w = 0; w < 8; ++w) kd += ws[e3][w][d3];
            if (stage == 0) {
                // midpoint state: zmid = z0 + (h/2) k1
                zin_s[e3][d3] = fmaf(0.5f * he, kd, zc);
            } else {
                // final: z1 = z0 + h k2
                out[(base + e3) * D + d3] = fmaf(he, kd, zc);
            }
        }
        __syncthreads();
    }
}

extern "C" void kernel_launch(void* const* d_in, const int* in_sizes, int n_in,
                              void* d_out, int out_size, void* d_ws, size_t ws_size,
                              hipStream_t stream) {
    const float* z_end = (const float*)d_in[0];
    const float* W1    = (const float*)d_in[1];
    const float* b1    = (const float*)d_in[2];
    const float* W2    = (const float*)d_in[3];
    const float* b2    = (const float*)d_in[4];
    float* out = (float*)d_out;
    const int n = in_sizes[0] / D;   // 2048

    ode_kernel<<<n / E, 512, 0, stream>>>(z_end, W1, b1, W2, b2, out, n);
}

// Round 7
// 67.043 us; speedup vs baseline: 1.0174x; 1.0174x over previous
//
#include <hip/hip_runtime.h>

// GenODE: z'(t) = tanh(z W1 + b1) W2 + b2, z_i(t_i) from z_i(0)=z_end[i],
// t_i = i/(N-1). SINGLE MIDPOINT (RK2) step with h = t_i:
//   k1 = f(z0); zmid = z0 + (h/2) k1; k2 = f(zmid); z1 = z0 + h k2.
// Validated R5/R6: absmax sits at the bf16 compare floor (0.0078125).
//
// R6 post-mortem: E=4/512blk and E=8/256blk equal wall time -> per-block
// critical path dominates at 1 block/CU. Root cause: __launch_bounds__
// arg2 is MIN WAVES PER EU; (512,2) gave the compiler a 256-VGPR budget ->
// >128 VGPRs -> 1 block/CU -> two sequential grid generations (R5) / 2x
// per-block path (R6). This round: (512,4) = 128-VGPR cap = 2 blocks/CU,
// one co-resident generation, 16 waves/CU latency hiding. Everything else
// identical to R5; FMA order unchanged so absmax must stay bit-exact.

constexpr int D = 32;
constexpr int H = 512;
constexpr int E = 4;

__device__ __forceinline__ float fast_tanh(float x) {
    // tanh(x) = 1 - 2/(exp(2x)+1); overflow -> inf -> rcp -> 0 -> +1 (correct)
    float e = __expf(2.0f * x);
    float r = __builtin_amdgcn_rcpf(e + 1.0f);
    return 1.0f - 2.0f * r;
}

__global__ __launch_bounds__(512, 4) void ode_kernel(
    const float* __restrict__ z_end, const float* __restrict__ W1,
    const float* __restrict__ b1, const float* __restrict__ W2,
    const float* __restrict__ b2, float* __restrict__ out, int n)
{
    __shared__ __align__(16) float zin_s[E][D];     // stage input z
    __shared__ __align__(16) float h_s[E][H];       // hidden activations
    __shared__ __align__(16) float ws[E][8][D];     // per-wave partials

    const int t  = (int)threadIdx.x;
    const int c_ = t >> 5;      // hidden chunk, 16 chunks of 32
    const int wv = t >> 6;      // wave id (8 waves)
    const int ln = t & 63;      // lane id

    const int base = (int)blockIdx.x * E;

    // Register-resident weights.
    float w1c[D];
#pragma unroll
    for (int d = 0; d < D; ++d) w1c[d] = W1[d * H + t];       // coalesced over t
    const float b1j = b1[t];
    float w2t[D];
#pragma unroll
    for (int k = 0; k < D; ++k) w2t[k] = W2[(c_ * 32 + k) * D + (t & 31)];

    // Phase-3 per-thread ODE state (threads 0..127: e3 = t>>5, d3 = t&31).
    float zc = 0.0f, b2d = 0.0f, he = 0.0f;
    if (t < E * D) {
        const int e3 = t >> 5, d3 = t & 31;
        zc  = z_end[(base + e3) * D + d3];
        b2d = b2[d3];
        he  = (float)(base + e3) / (float)(n - 1);   // h = t_i (single step)
        zin_s[e3][d3] = zc;
    }
    __syncthreads();

#pragma unroll
    for (int stage = 0; stage < 2; ++stage) {
        // ---- phase1: hidden_j = tanh(zin . W1col_j + b1_j), all E elems ----
        float a[E];
#pragma unroll
        for (int e = 0; e < E; ++e) {
            const float4* z4 = (const float4*)zin_s[e];   // broadcast b128 reads
            float acc = b1j;
#pragma unroll
            for (int q = 0; q < 8; ++q) {
                float4 zv = z4[q];
                acc = fmaf(zv.x, w1c[4 * q + 0], acc);
                acc = fmaf(zv.y, w1c[4 * q + 1], acc);
                acc = fmaf(zv.z, w1c[4 * q + 2], acc);
                acc = fmaf(zv.w, w1c[4 * q + 3], acc);
            }
            a[e] = acc;
        }
#pragma unroll
        for (int e = 0; e < E; ++e) h_s[e][t] = fast_tanh(a[e]);
        __syncthreads();

        // ---- phase2: chunk-partial of k_d = sum_j h_j W2[j][d] ----
        float p[E];
#pragma unroll
        for (int e = 0; e < E; ++e) {
            const float4* h4 = (const float4*)&h_s[e][c_ * 32];
            float acc = 0.0f;
#pragma unroll
            for (int q = 0; q < 8; ++q) {
                float4 hv = h4[q];
                acc = fmaf(hv.x, w2t[4 * q + 0], acc);
                acc = fmaf(hv.y, w2t[4 * q + 1], acc);
                acc = fmaf(hv.z, w2t[4 * q + 2], acc);
                acc = fmaf(hv.w, w2t[4 * q + 3], acc);
            }
            p[e] = acc;
        }
#pragma unroll
        for (int e = 0; e < E; ++e) p[e] += __shfl_down(p[e], 32);
        if (ln < 32) {
#pragma unroll
            for (int e = 0; e < E; ++e) ws[e][wv][ln] = p[e];
        }
        __syncthreads();

        // ---- phase3: finish k_d, RK2 stage update (threads 0..127) ----
        if (t < E * D) {
            const int e3 = t >> 5, d3 = t & 31;
            float kd = b2d;
#pragma unroll
            for (int w = 0; w < 8; ++w) kd += ws[e3][w][d3];
            if (stage == 0) {
                // midpoint state: zmid = z0 + (h/2) k1
                zin_s[e3][d3] = fmaf(0.5f * he, kd, zc);
            } else {
                // final: z1 = z0 + h k2
                out[(base + e3) * D + d3] = fmaf(he, kd, zc);
            }
        }
        __syncthreads();
    }
}

extern "C" void kernel_launch(void* const* d_in, const int* in_sizes, int n_in,
                              void* d_out, int out_size, void* d_ws, size_t ws_size,
                              hipStream_t stream) {
    const float* z_end = (const float*)d_in[0];
    const float* W1    = (const float*)d_in[1];
    const float* b1    = (const float*)d_in[2];
    const float* W2    = (const float*)d_in[3];
    const float* b2    = (const float*)d_in[4];
    float* out = (float*)d_out;
    const int n = in_sizes[0] / D;   // 2048

    ode_kernel<<<n / E, 512, 0, stream>>>(z_end, W1, b1, W2, b2, out, n);
}